// Round 2
// baseline (988.813 us; speedup 1.0000x reference)
//
#include <hip/hip_runtime.h>

#define BB 8
#define NN 4096
#define DD 64
#define SS 1024
#define KK 32
#define R2 0.04f

typedef float f32x2 __attribute__((ext_vector_type(2)));

// One DPP max stage: wv = max(wv, lanes-shifted wv). old = self -> invalid lanes
// contribute identity. row_shr:1,2,4,8 + row_bcast:15,31 -> lane 63 has wave max.
#define DPP_MAXF(wv, CTRL)                                                             \
    {                                                                                  \
        int _o = __builtin_amdgcn_update_dpp(__float_as_int(wv), __float_as_int(wv),   \
                                             CTRL, 0xf, 0xf, false);                   \
        (wv) = fmaxf((wv), __int_as_float(_o));                                        \
    }

// One stage of the 8-record cross-wave butterfly. Payload {~cand, valbits, x, y, z};
// key = (u64)valbits<<32 | ~cand, so u64-max == (max val, min cand idx). All-VALU
// (DPP quad_perm / row_half_mirror), no LDS traffic, every lane ends with the winner.
// Set-max argument: after xor1+xor2 each lane holds max over its quad of records;
// row_half_mirror (l -> 7-l within each 8-group) pairs each lane with one from the
// OTHER quad, so the final max covers all 8 distinct records held by the 8-group.
#define XCH_STAGE(CTRL)                                                                \
    {                                                                                  \
        const unsigned o_lo = (unsigned)__builtin_amdgcn_update_dpp(                   \
            (int)r_lo, (int)r_lo, CTRL, 0xf, 0xf, false);                              \
        const unsigned o_hi = (unsigned)__builtin_amdgcn_update_dpp(                   \
            (int)r_hi, (int)r_hi, CTRL, 0xf, 0xf, false);                              \
        const unsigned o_x = (unsigned)__builtin_amdgcn_update_dpp(                    \
            (int)r_x, (int)r_x, CTRL, 0xf, 0xf, false);                                \
        const unsigned o_y = (unsigned)__builtin_amdgcn_update_dpp(                    \
            (int)r_y, (int)r_y, CTRL, 0xf, 0xf, false);                                \
        const unsigned o_z = (unsigned)__builtin_amdgcn_update_dpp(                    \
            (int)r_z, (int)r_z, CTRL, 0xf, 0xf, false);                                \
        const unsigned long long _m = ((unsigned long long)r_hi << 32) | r_lo;         \
        const unsigned long long _o = ((unsigned long long)o_hi << 32) | o_lo;         \
        const bool _tk = _o > _m;                                                      \
        r_lo = _tk ? o_lo : r_lo;                                                      \
        r_hi = _tk ? o_hi : r_hi;                                                      \
        r_x  = _tk ? o_x : r_x;                                                        \
        r_y  = _tk ? o_y : r_y;                                                        \
        r_z  = _tk ? o_z : r_z;                                                        \
    }

// Redundant-FPS design: 256 blocks x 512 thr, one per CU (static LDS 82176 B >
// 160KiB/2 forces 1 block/CU). Block handles batch b = blk>>5 and group chunk
// cs = blk&31: it runs FPS for its batch up to step cs*32+32 (identical,
// deterministic work replicated across the blocks of that batch — the whole
// per-step pipeline is atomic-free: fminf updates, DPP reduce, and a
// register-carried winner record make every block compute bit-identical sfar),
// then serves its own 32 groups (ball query + output) entirely from its own LDS.
// NO cross-block synchronization exists.
//
// Per-step exchange: instead of
//   atomicMax(red[t]) -> barrier -> ds_read red[t] -> ds_read sxyz[far]
// (3 dependent LDS round-trips + 8-way same-address atomic), the winning lane of
// each wave writes {~cand, val, x, y, z} to a double-buffered per-wave slot;
// after the single barrier, lanes read record (lane&7) (32B stride -> 2-way bank
// aliasing, free) and a 3-stage DPP butterfly yields the global winner WITH its
// coordinates in registers -> next step's distance math starts with zero further
// LDS dependency. Double-buffering (t&1) makes one-barrier-per-step race-free:
// a wave can run at most one barrier ahead (it would block at barrier t+1 until
// all waves consumed buffer t&1) and it only writes buffer (t+1)&1.
__global__ __launch_bounds__(512) void fused_kernel(const float* __restrict__ xyz,
                                                    const float* __restrict__ points,
                                                    float* __restrict__ out) {
#pragma clang fp contract(off)
    __shared__ float4 sxyz[NN];                    // 64 KB {x,y,z,pad}
    __shared__ unsigned long long lpad[1376];      // 11 KB LDS occupancy pad (kept live)
    __shared__ int sfar[SS];                       // 4 KB FPS index history
    __shared__ int bbuf[8][KK];                    // 1 KB per-wave ball lists
    __shared__ __align__(16) unsigned wrec[2][8][8]; // 512 B dbuf'd per-wave winner recs
    // total 65536+11008+4096+1024+512 = 82176 B (same as the verified 739us kernel)

    const int tid  = threadIdx.x;
    const int wave = tid >> 6;
    const int lane = tid & 63;
    const int b    = blockIdx.x >> 5;              // batch
    const int cs   = blockIdx.x & 31;              // group chunk within batch
    const float* xb = xyz + (size_t)b * NN * 3;
    const float* pb = points + (size_t)b * NN * DD;

    for (int i = tid; i < 1376; i += 512) lpad[i] = 0ull;   // touch pad: keep allocated

    // ---- init: 96 contiguous bytes per lane (8 points x 3 floats) via 6x float4 ----
    const float4* xb4 = (const float4*)(xb + tid * 24);
    const float4 q0 = xb4[0], q1 = xb4[1], q2 = xb4[2];
    const float4 q3 = xb4[3], q4 = xb4[4], q5 = xb4[5];

    f32x2 px[4], py[4], pz[4], dist[4];
    px[0] = (f32x2){q0.x, q0.w}; py[0] = (f32x2){q0.y, q1.x}; pz[0] = (f32x2){q0.z, q1.y};
    px[1] = (f32x2){q1.z, q2.y}; py[1] = (f32x2){q1.w, q2.z}; pz[1] = (f32x2){q2.x, q2.w};
    px[2] = (f32x2){q3.x, q3.w}; py[2] = (f32x2){q3.y, q4.x}; pz[2] = (f32x2){q3.z, q4.y};
    px[3] = (f32x2){q4.z, q5.y}; py[3] = (f32x2){q4.w, q5.z}; pz[3] = (f32x2){q5.x, q5.w};
#pragma unroll
    for (int jj = 0; jj < 4; ++jj) {
        const int i0 = tid * 8 + 2 * jj;
        sxyz[i0]     = make_float4(px[jj].x, py[jj].x, pz[jj].x, 0.0f);
        sxyz[i0 + 1] = make_float4(px[jj].y, py[jj].y, pz[jj].y, 0.0f);
        dist[jj] = (f32x2){1e10f, 1e10f};
    }
    __syncthreads();                               // also orders lpad writes < reads

    // ================= FPS (replicated per block; zero global ops) =================
    int far = (int)(unsigned)lpad[0];              // == 0; also keeps lpad live
    const float4 c0 = sxyz[far];                   // one-time centroid-0 coords
    float ccx = c0.x, ccy = c0.y, ccz = c0.z;

    const int tmax = cs * 32 + 32;                 // this block only needs sfar[0..tmax)
    for (int t = 0; t < tmax; ++t) {
        if (tid == 0) sfar[t] = far;               // scan emits pre-update carry
        const f32x2 cx2 = (f32x2){ccx, ccx}, cy2 = (f32x2){ccy, ccy},
                    cz2 = (f32x2){ccz, ccz};

        f32x2 nd[4];
#pragma unroll
        for (int jj = 0; jj < 4; ++jj) {
            // exact ref order: ((dx^2 + dy^2) + dz^2); contract(off) => no FMA
            const f32x2 dx = px[jj] - cx2;
            const f32x2 dy = py[jj] - cy2;
            const f32x2 dz = pz[jj] - cz2;
            const f32x2 d  = (dx * dx + dy * dy) + dz * dz;
            f32x2 m;
            m.x = fminf(dist[jj].x, d.x);          // fmin exact; order-independent
            m.y = fminf(dist[jj].y, d.y);
            dist[jj] = m;
            nd[jj] = m;
        }
        // per-lane max, grouped for v_max3_f32 fusion (4 insts, depth 3; values
        // non-negative, no NaN)
        const float t0 = fmaxf(fmaxf(nd[0].x, nd[0].y), nd[1].x);   // max3
        const float t1 = fmaxf(fmaxf(nd[1].y, nd[2].x), nd[2].y);   // max3
        const float t2 = fmaxf(nd[3].x, nd[3].y);
        const float bestv = fmaxf(fmaxf(t0, t1), t2);               // max3
        // smallest j achieving it (descending scan => first match wins); carry the
        // candidate's coordinates so the winner never needs an sxyz[] readback
        int localj = 0;
        float candx = px[0].x, candy = py[0].x, candz = pz[0].x;
#pragma unroll
        for (int j = 7; j >= 0; --j) {
            const float v = (j & 1) ? nd[j >> 1].y : nd[j >> 1].x;
            if (v == bestv) {
                localj = j;
                candx = (j & 1) ? px[j >> 1].y : px[j >> 1].x;
                candy = (j & 1) ? py[j >> 1].y : py[j >> 1].x;
                candz = (j & 1) ? pz[j >> 1].y : pz[j >> 1].x;
            }
        }

        // wave max via fused DPP f32 max; first matching lane owns the wave record
        float wv = bestv;
        DPP_MAXF(wv, 0x111);   // row_shr:1
        DPP_MAXF(wv, 0x112);   // row_shr:2
        DPP_MAXF(wv, 0x114);   // row_shr:4
        DPP_MAXF(wv, 0x118);   // row_shr:8
        DPP_MAXF(wv, 0x142);   // row_bcast:15
        DPP_MAXF(wv, 0x143);   // row_bcast:31
        const float maxw =
            __int_as_float(__builtin_amdgcn_readlane(__float_as_int(wv), 63));

        const unsigned long long hits = __ballot(bestv == maxw);
        const int L = __ffsll(hits) - 1;           // smallest lane == smallest global idx
        if (lane == L) {                           // winner writes its own record
            unsigned* rr = &wrec[t & 1][wave][0];
            ((uint4*)rr)[0] = make_uint4(~(unsigned)(tid * 8 + localj),
                                         __float_as_uint(bestv),
                                         __float_as_uint(candx),
                                         __float_as_uint(candy));
            rr[4] = __float_as_uint(candz);
        }
        __syncthreads();                           // the only barrier in the step

        // read the 8 wave records (lane&7 spread: 2-way bank aliasing, free) and
        // butterfly-reduce in registers; every lane gets {val, idx, x, y, z}
        const unsigned* rr = &wrec[t & 1][lane & 7][0];
        const uint4 ra = *((const uint4*)rr);
        unsigned r_lo = ra.x, r_hi = ra.y, r_x = ra.z, r_y = ra.w, r_z = rr[4];
        XCH_STAGE(0xB1);    // quad_perm [1,0,3,2]  (xor 1)
        XCH_STAGE(0x4E);    // quad_perm [2,3,0,1]  (xor 2)
        XCH_STAGE(0x141);   // row_half_mirror      (covers the other quad of 8)
        far = (int)~r_lo;                          // next centroid index (for sfar)
        ccx = __uint_as_float(r_x);                // next centroid coords, already in
        ccy = __uint_as_float(r_y);                // registers: no sxyz[far] read on
        ccz = __uint_as_float(r_z);                // the critical path
    }
    // sfar[] fully visible: each sfar[t] write precedes that step's barrier.

    // ============ this block's 32 groups: ball query + output, all from LDS ============
#pragma unroll
    for (int i = 0; i < 4; ++i) {
        const int s  = cs * 32 + wave * 4 + i;     // group within batch (s < tmax)
        const int g  = b * SS + s;                 // flat group id
        const int qi = sfar[s];
        const float4 q = sxyz[qi];
        const float qn = __fadd_rn(__fadd_rn(__fmul_rn(q.x, q.x), __fmul_rn(q.y, q.y)),
                                   __fmul_rn(q.z, q.z));

        int total = 0;
        for (int base = 0; base < NN && total < KK; base += 64) {
            const int n = base + lane;
            const float4 p = sxyz[n];              // ds_read_b128; values == global xyz
            const float pn = __fadd_rn(__fadd_rn(__fmul_rn(p.x, p.x), __fmul_rn(p.y, p.y)),
                                       __fmul_rn(p.z, p.z));
            const float dt = __fadd_rn(__fadd_rn(__fmul_rn(q.x, p.x), __fmul_rn(q.y, p.y)),
                                       __fmul_rn(q.z, p.z));
            // exact ref order: d = (-2*dot) + |q|^2 + |p|^2
            const float d = __fadd_rn(__fadd_rn(__fmul_rn(-2.0f, dt), qn), pn);
            const bool hit = !(d > R2);            // include iff d <= r^2
            const unsigned long long mask = __ballot(hit);
            const int before = __popcll(mask & ((1ull << lane) - 1ull));
            const int pos = total + before;
            if (hit && pos < KK) bbuf[wave][pos] = n;
            total += (int)__popcll(mask);
        }
        // pad with first element (wave-synchronous LDS, no barrier needed)
        if (lane < KK) {
            const int v = (lane < total) ? bbuf[wave][lane] : bbuf[wave][0];
            bbuf[wave][lane] = v;
        }

        // new_xyz
        if (lane < 3)
            out[(size_t)g * 3 + lane] = (lane == 0) ? q.x : (lane == 1) ? q.y : q.z;

        // anchor feature columns this lane is responsible for (same for all k)
        const float a1 = (lane >= 3) ? pb[qi * DD + (lane - 3)] : 0.0f;  // cols 67..127
        const float a2 = (lane < 3) ? pb[qi * DD + (61 + lane)] : 0.0f;  // cols 128..130

        float* outp = out + (size_t)BB * SS * 3 + (size_t)g * (KK * 131);
        for (int k = 0; k < KK; ++k) {
            const int idx = bbuf[wave][k];
            const float4 pi = sxyz[idx];
            outp[k * 131 + lane] = pb[idx * DD + lane];                    // cols 0..63
            const float v1 = (lane == 0) ? pi.x
                           : (lane == 1) ? pi.y
                           : (lane == 2) ? pi.z
                                         : a1;                             // cols 64..127
            outp[k * 131 + 64 + lane] = v1;
            if (lane < 3) outp[k * 131 + 128 + lane] = a2;                 // cols 128..130
        }
    }
}

extern "C" void kernel_launch(void* const* d_in, const int* in_sizes, int n_in,
                              void* d_out, int out_size, void* d_ws, size_t ws_size,
                              hipStream_t stream) {
    const float* xyz    = (const float*)d_in[0];   // [B,N,3]
    const float* points = (const float*)d_in[1];   // [B,N,D]
    float* out = (float*)d_out;

    fused_kernel<<<BB * 32, 512, 0, stream>>>(xyz, points, out);
}

// Round 5
// 829.798 us; speedup vs baseline: 1.1916x; 1.1916x over previous
//
#include <hip/hip_runtime.h>

#define BB 8
#define NN 4096
#define DD 64
#define SS 1024
#define KK 32
#define R2 0.04f

typedef float f32x2 __attribute__((ext_vector_type(2)));

// One DPP max stage: wv = max(wv, lanes-shifted wv). old = self -> invalid lanes
// contribute identity. row_shr:1,2,4,8 + row_bcast:15,31 -> lane 63 has wave max.
#define DPP_MAXF(wv, CTRL)                                                             \
    {                                                                                  \
        int _o = __builtin_amdgcn_update_dpp(__float_as_int(wv), __float_as_int(wv),   \
                                             CTRL, 0xf, 0xf, false);                   \
        (wv) = fmaxf((wv), __int_as_float(_o));                                        \
    }

// One stage of the 8-slot cross-wave butterfly, LEAN 2-word payload (u64 key =
// valbits<<32 | ~cand, so u64-max == (max val, min cand idx)). 2 DPP movs + one
// u64 compare + 2 selects per stage. Set-max argument: xor1+xor2 give each lane
// the max over its quad of slots; row_half_mirror (l -> l^7 within each 8-group)
// pairs each lane with the other quad, so all 8 slots are covered.
#define XCH2(CTRL)                                                                     \
    {                                                                                  \
        const unsigned o_lo = (unsigned)__builtin_amdgcn_update_dpp(                   \
            (int)r_lo, (int)r_lo, CTRL, 0xf, 0xf, false);                              \
        const unsigned o_hi = (unsigned)__builtin_amdgcn_update_dpp(                   \
            (int)r_hi, (int)r_hi, CTRL, 0xf, 0xf, false);                              \
        const unsigned long long _m = ((unsigned long long)r_hi << 32) | r_lo;         \
        const unsigned long long _o = ((unsigned long long)o_hi << 32) | o_lo;         \
        const bool _tk = _o > _m;                                                      \
        r_lo = _tk ? o_lo : r_lo;                                                      \
        r_hi = _tk ? o_hi : r_hi;                                                      \
    }

// Redundant-FPS design: 256 blocks x 512 thr, one per CU (static LDS 82048 B >
// 160KiB/2 forces 1 block/CU). Block handles batch b = blk>>5 and group chunk
// cs = blk&31: it runs FPS for its batch up to step cs*32+32 (identical,
// deterministic, replicated work), then serves its own 32 groups (ball query +
// output) entirely from its own LDS. NO cross-block synchronization exists.
//
// R3 exchange (the single change vs the 739us baseline, plus early-exit tmax):
// the baseline's 8-way same-address LDS atomicMax is replaced by a plain
// per-wave ds_write_b64 of the packed key into a double-buffered slot;
// post-barrier, one conflict-free ds_read_b64 of slot (lane&7) + a 3-stage
// 2-word DPP butterfly gives every lane the block winner. Loop shape otherwise
// identical to the baseline (top-of-step sxyz[far] broadcast read, index-only
// tie-break scan) — R0's fat 5-word butterfly and coordinate-carrying scan are
// REMOVED (measured +380 cyc/step in R2). Double-buffering (t&1) makes
// one-barrier-per-step race-free: to overwrite buffer t&1 at step t+2 a wave
// must pass barrier t+1, which requires all waves to have read buffer t&1.
__global__ __launch_bounds__(512) void fused_kernel(const float* __restrict__ xyz,
                                                    const float* __restrict__ points,
                                                    float* __restrict__ out) {
#pragma clang fp contract(off)
    __shared__ float4 sxyz[NN];                    // 65536 B {x,y,z,pad}
    __shared__ unsigned long long lpad[1408];      // 11264 B LDS occupancy pad (live)
    __shared__ int sfar[SS];                       // 4096 B FPS index history
    __shared__ int bbuf[8][KK];                    // 1024 B per-wave ball lists
    __shared__ unsigned long long wrec8[2][8];     // 128 B dbuf'd per-wave winner keys
    // total 65536+11264+4096+1024+128 = 82048 B > 81920 => 1 block/CU guaranteed

    const int tid  = threadIdx.x;
    const int wave = tid >> 6;
    const int lane = tid & 63;
    const int b    = blockIdx.x >> 5;              // batch
    const int cs   = blockIdx.x & 31;              // group chunk within batch
    const float* xb = xyz + (size_t)b * NN * 3;
    const float* pb = points + (size_t)b * NN * DD;

    for (int i = tid; i < 1408; i += 512) lpad[i] = 0ull;   // touch pad: keep allocated

    // ---- init: 96 contiguous bytes per lane (8 points x 3 floats) via 6x float4 ----
    const float4* xb4 = (const float4*)(xb + tid * 24);
    const float4 q0 = xb4[0], q1 = xb4[1], q2 = xb4[2];
    const float4 q3 = xb4[3], q4 = xb4[4], q5 = xb4[5];

    f32x2 px[4], py[4], pz[4], dist[4];
    px[0] = (f32x2){q0.x, q0.w}; py[0] = (f32x2){q0.y, q1.x}; pz[0] = (f32x2){q0.z, q1.y};
    px[1] = (f32x2){q1.z, q2.y}; py[1] = (f32x2){q1.w, q2.z}; pz[1] = (f32x2){q2.x, q2.w};
    px[2] = (f32x2){q3.x, q3.w}; py[2] = (f32x2){q3.y, q4.x}; pz[2] = (f32x2){q3.z, q4.y};
    px[3] = (f32x2){q4.z, q5.y}; py[3] = (f32x2){q4.w, q5.z}; pz[3] = (f32x2){q5.x, q5.w};
#pragma unroll
    for (int jj = 0; jj < 4; ++jj) {
        const int i0 = tid * 8 + 2 * jj;
        sxyz[i0]     = make_float4(px[jj].x, py[jj].x, pz[jj].x, 0.0f);
        sxyz[i0 + 1] = make_float4(px[jj].y, py[jj].y, pz[jj].y, 0.0f);
        dist[jj] = (f32x2){1e10f, 1e10f};
    }
    __syncthreads();                               // also orders lpad writes < reads

    // ================= FPS (replicated per block; zero global ops) =================
    int far = (int)(unsigned)lpad[0];              // == 0; also keeps lpad live

    const int tmax = cs * 32 + 32;                 // this block only needs sfar[0..tmax)
    for (int t = 0; t < tmax; ++t) {
        if (tid == 0) sfar[t] = far;               // scan emits pre-update carry
        const float4 c = sxyz[far];                // one ds_read_b128 (broadcast)
        const f32x2 cx2 = (f32x2){c.x, c.x}, cy2 = (f32x2){c.y, c.y},
                    cz2 = (f32x2){c.z, c.z};

        f32x2 nd[4];
#pragma unroll
        for (int jj = 0; jj < 4; ++jj) {
            // exact ref order: ((dx^2 + dy^2) + dz^2); contract(off) => no FMA
            const f32x2 dx = px[jj] - cx2;
            const f32x2 dy = py[jj] - cy2;
            const f32x2 dz = pz[jj] - cz2;
            const f32x2 d  = (dx * dx + dy * dy) + dz * dz;
            f32x2 m;
            m.x = fminf(dist[jj].x, d.x);          // fmin exact; order-independent
            m.y = fminf(dist[jj].y, d.y);
            dist[jj] = m;
            nd[jj] = m;
        }
        // per-lane max, grouped for v_max3_f32 fusion (4 insts; values non-neg, no NaN)
        const float t0 = fmaxf(fmaxf(nd[0].x, nd[0].y), nd[1].x);   // max3
        const float t1 = fmaxf(fmaxf(nd[1].y, nd[2].x), nd[2].y);   // max3
        const float t2 = fmaxf(nd[3].x, nd[3].y);
        const float bestv = fmaxf(fmaxf(t0, t1), t2);               // max3
        // smallest j achieving it (descending scan => first match wins), index only;
        // off the critical path (runs in parallel with the DPP reduce below)
        int localj = 0;
#pragma unroll
        for (int j = 7; j >= 0; --j) {
            const float v = (j & 1) ? nd[j >> 1].y : nd[j >> 1].x;
            if (v == bestv) localj = j;
        }

        // wave max via fused DPP f32 max; first matching lane owns the wave slot
        float wv = bestv;
        DPP_MAXF(wv, 0x111);   // row_shr:1
        DPP_MAXF(wv, 0x112);   // row_shr:2
        DPP_MAXF(wv, 0x114);   // row_shr:4
        DPP_MAXF(wv, 0x118);   // row_shr:8
        DPP_MAXF(wv, 0x142);   // row_bcast:15
        DPP_MAXF(wv, 0x143);   // row_bcast:31
        const float maxw =
            __int_as_float(__builtin_amdgcn_readlane(__float_as_int(wv), 63));

        const unsigned long long hits = __ballot(bestv == maxw);
        const int L = __ffsll(hits) - 1;           // smallest lane == smallest global idx
        if (lane == L) {                           // winner: one plain ds_write_b64
            wrec8[t & 1][wave] =
                ((unsigned long long)__float_as_uint(bestv) << 32) |
                (unsigned)~(unsigned)(tid * 8 + localj);
        }
        __syncthreads();                           // the only barrier in the step

        // one conflict-free ds_read_b64 (8 slots x 8B -> banks 0..15, lanes sharing
        // a slot broadcast) + 3-stage 2-word butterfly => block winner on every lane
        const unsigned long long k8 = wrec8[t & 1][lane & 7];
        unsigned r_lo = (unsigned)k8, r_hi = (unsigned)(k8 >> 32);
        XCH2(0xB1);     // quad_perm [1,0,3,2]  (xor 1)
        XCH2(0x4E);     // quad_perm [2,3,0,1]  (xor 2)
        XCH2(0x141);    // row_half_mirror      (covers the other quad of 8)
        far = (int)~r_lo;                          // next centroid index
    }
    // sfar[] fully visible: each sfar[t] write precedes that step's barrier.

    // ============ this block's 32 groups: ball query + output, all from LDS ============
#pragma unroll
    for (int i = 0; i < 4; ++i) {
        const int s  = cs * 32 + wave * 4 + i;     // group within batch (s < tmax)
        const int g  = b * SS + s;                 // flat group id
        const int qi = sfar[s];
        const float4 q = sxyz[qi];
        const float qn = __fadd_rn(__fadd_rn(__fmul_rn(q.x, q.x), __fmul_rn(q.y, q.y)),
                                   __fmul_rn(q.z, q.z));

        int total = 0;
        for (int base = 0; base < NN && total < KK; base += 64) {
            const int n = base + lane;
            const float4 p = sxyz[n];              // ds_read_b128; values == global xyz
            const float pn = __fadd_rn(__fadd_rn(__fmul_rn(p.x, p.x), __fmul_rn(p.y, p.y)),
                                       __fmul_rn(p.z, p.z));
            const float dt = __fadd_rn(__fadd_rn(__fmul_rn(q.x, p.x), __fmul_rn(q.y, p.y)),
                                       __fmul_rn(q.z, p.z));
            // exact ref order: d = (-2*dot) + |q|^2 + |p|^2
            const float d = __fadd_rn(__fadd_rn(__fmul_rn(-2.0f, dt), qn), pn);
            const bool hit = !(d > R2);            // include iff d <= r^2
            const unsigned long long mask = __ballot(hit);
            const int before = __popcll(mask & ((1ull << lane) - 1ull));
            const int pos = total + before;
            if (hit && pos < KK) bbuf[wave][pos] = n;
            total += (int)__popcll(mask);
        }
        // pad with first element (wave-synchronous LDS, no barrier needed)
        if (lane < KK) {
            const int v = (lane < total) ? bbuf[wave][lane] : bbuf[wave][0];
            bbuf[wave][lane] = v;
        }

        // new_xyz
        if (lane < 3)
            out[(size_t)g * 3 + lane] = (lane == 0) ? q.x : (lane == 1) ? q.y : q.z;

        // anchor feature columns this lane is responsible for (same for all k)
        const float a1 = (lane >= 3) ? pb[qi * DD + (lane - 3)] : 0.0f;  // cols 67..127
        const float a2 = (lane < 3) ? pb[qi * DD + (61 + lane)] : 0.0f;  // cols 128..130

        float* outp = out + (size_t)BB * SS * 3 + (size_t)g * (KK * 131);
        for (int k = 0; k < KK; ++k) {
            const int idx = bbuf[wave][k];
            const float4 pi = sxyz[idx];
            outp[k * 131 + lane] = pb[idx * DD + lane];                    // cols 0..63
            const float v1 = (lane == 0) ? pi.x
                           : (lane == 1) ? pi.y
                           : (lane == 2) ? pi.z
                                         : a1;                             // cols 64..127
            outp[k * 131 + 64 + lane] = v1;
            if (lane < 3) outp[k * 131 + 128 + lane] = a2;                 // cols 128..130
        }
    }
}

extern "C" void kernel_launch(void* const* d_in, const int* in_sizes, int n_in,
                              void* d_out, int out_size, void* d_ws, size_t ws_size,
                              hipStream_t stream) {
    const float* xyz    = (const float*)d_in[0];   // [B,N,3]
    const float* points = (const float*)d_in[1];   // [B,N,D]
    float* out = (float*)d_out;

    fused_kernel<<<BB * 32, 512, 0, stream>>>(xyz, points, out);
}